// Round 1
// baseline (660.249 us; speedup 1.0000x reference)
//
#include <hip/hip_runtime.h>

#define NFEAT 128
#define DOUT 48

// ---------------- kernel A: h = feat @ W^T + b ; s_src/s_dst dots ----------------
__global__ __launch_bounds__(256) void k_proj(
    const float* __restrict__ feat, const float* __restrict__ Ww,
    const float* __restrict__ Wb, const float* __restrict__ attn_w,
    float* __restrict__ h, float* __restrict__ s_src, float* __restrict__ s_dst,
    int n)
{
    int node = blockIdx.x * 256 + threadIdx.x;
    if (node >= n) return;

    float4 f[NFEAT / 4];
    const float4* fp = (const float4*)(feat + (size_t)node * NFEAT);
#pragma unroll
    for (int i = 0; i < NFEAT / 4; ++i) f[i] = fp[i];

    float hv[DOUT];
    for (int j = 0; j < DOUT; ++j) {
        const float4* wp = (const float4*)(Ww + (size_t)j * NFEAT);  // wave-uniform -> s_load
        float acc = Wb[j];
#pragma unroll
        for (int i = 0; i < NFEAT / 4; ++i) {
            float4 w = wp[i];
            acc = fmaf(f[i].x, w.x, acc);
            acc = fmaf(f[i].y, w.y, acc);
            acc = fmaf(f[i].z, w.z, acc);
            acc = fmaf(f[i].w, w.w, acc);
        }
        hv[j] = acc;
    }

    float ss = 0.f, sd = 0.f;
#pragma unroll
    for (int j = 0; j < DOUT; ++j) {
        ss = fmaf(hv[j], attn_w[j], ss);
        sd = fmaf(hv[j], attn_w[DOUT + j], sd);
    }

    float4* hp = (float4*)(h + (size_t)node * DOUT);
#pragma unroll
    for (int i = 0; i < DOUT / 4; ++i)
        hp[i] = make_float4(hv[4 * i], hv[4 * i + 1], hv[4 * i + 2], hv[4 * i + 3]);
    s_src[node] = ss;
    s_dst[node] = sd;
}

// ---------------- monotone float<->uint encoding for atomicMax ----------------
__device__ __forceinline__ unsigned f2ord(float f) {
    unsigned u = __float_as_uint(f);
    return (u & 0x80000000u) ? ~u : (u | 0x80000000u);
}
__device__ __forceinline__ float ord2f(unsigned u) {
    return (u & 0x80000000u) ? __uint_as_float(u ^ 0x80000000u) : __uint_as_float(~u);
}

// ---------------- kernel B: per-edge score + segment max ----------------
__global__ __launch_bounds__(256) void k_edge_max(
    const float* __restrict__ s_src, const float* __restrict__ s_dst,
    const float* __restrict__ attn_b,
    const int* __restrict__ src, const int* __restrict__ dst,
    float* __restrict__ e_out, unsigned* __restrict__ mord, int nE)
{
    int e = blockIdx.x * 256 + threadIdx.x;
    if (e >= nE) return;
    int s = src[e], d = dst[e];
    float v = s_src[s] + s_dst[d] + attn_b[0];
    v = (v > 0.f) ? v : 0.2f * v;  // leaky_relu slope 0.2
    e_out[e] = v;
    atomicMax(mord + d, f2ord(v));
}

// ---------------- kernel C: ex = exp(e - m[dst]); denom += ex ----------------
__global__ __launch_bounds__(256) void k_edge_exp(
    const float* __restrict__ e_in, const unsigned* __restrict__ mord,
    const int* __restrict__ dst,
    float* __restrict__ ex_out, float* __restrict__ denom, int nE)
{
    int e = blockIdx.x * 256 + threadIdx.x;
    if (e >= nE) return;
    int d = dst[e];
    float m = ord2f(mord[d]);
    float x = expf(e_in[e] - m);
    ex_out[e] = x;
    atomicAdd(denom + d, x);
}

// ---------------- kernel D: out[dst] += h[src] * alpha ----------------
__global__ __launch_bounds__(256) void k_scatter(
    const float* __restrict__ h, const float* __restrict__ ex,
    const float* __restrict__ denom,
    const int* __restrict__ src, const int* __restrict__ dst,
    float* __restrict__ out, int nE)
{
    long long tid = (long long)blockIdx.x * 256 + threadIdx.x;
    long long total = (long long)nE * DOUT;
    if (tid >= total) return;
    int e = (int)(tid / DOUT);
    int j = (int)(tid - (long long)e * DOUT);
    int d = dst[e];
    float alpha = ex[e] / denom[d];
    atomicAdd(out + (size_t)d * DOUT + j, h[(size_t)src[e] * DOUT + j] * alpha);
}

extern "C" void kernel_launch(void* const* d_in, const int* in_sizes, int n_in,
                              void* d_out, int out_size, void* d_ws, size_t ws_size,
                              hipStream_t stream) {
    const float* feat   = (const float*)d_in[0];
    const float* Ww     = (const float*)d_in[1];
    const float* Wb     = (const float*)d_in[2];
    const float* attn_w = (const float*)d_in[3];
    const float* attn_b = (const float*)d_in[4];
    const int*   src    = (const int*)d_in[5];
    const int*   dst    = (const int*)d_in[6];

    int n  = in_sizes[0] / NFEAT;   // 100000
    int nE = in_sizes[5];           // 1600000
    float* out = (float*)d_out;

    // workspace layout (floats)
    float* ws      = (float*)d_ws;
    float* h       = ws;                          // n*48
    float* s_src   = h + (size_t)n * DOUT;        // n
    float* s_dst   = s_src + n;                   // n
    unsigned* mord = (unsigned*)(s_dst + n);      // n
    float* denom   = (float*)(mord + n);          // n
    float* ework   = denom + n;                   // nE (e scores, then ex in place)

    // per-call init (ws/out are re-poisoned before every timed call)
    hipMemsetAsync(out,   0, (size_t)n * DOUT * sizeof(float), stream);
    hipMemsetAsync(mord,  0, (size_t)n * sizeof(unsigned), stream);  // ord(-inf) < 1
    hipMemsetAsync(denom, 0, (size_t)n * sizeof(float), stream);

    k_proj<<<(n + 255) / 256, 256, 0, stream>>>(feat, Ww, Wb, attn_w, h, s_src, s_dst, n);
    k_edge_max<<<(nE + 255) / 256, 256, 0, stream>>>(s_src, s_dst, attn_b, src, dst, ework, mord, nE);
    k_edge_exp<<<(nE + 255) / 256, 256, 0, stream>>>(ework, mord, dst, ework, denom, nE);
    long long total = (long long)nE * DOUT;
    k_scatter<<<(int)((total + 255) / 256), 256, 0, stream>>>(h, ework, denom, src, dst, out, nE);
}

// Round 2
// 649.574 us; speedup vs baseline: 1.0164x; 1.0164x over previous
//
#include <hip/hip_runtime.h>

#define NFEAT 128
#define DOUT 48

// ---------------- kernel A: h = feat @ W^T + b ; s_src/s_dst dots ----------------
__global__ __launch_bounds__(256) void k_proj(
    const float* __restrict__ feat, const float* __restrict__ Ww,
    const float* __restrict__ Wb, const float* __restrict__ attn_w,
    float* __restrict__ h, float* __restrict__ s_src, float* __restrict__ s_dst,
    int n)
{
    int node = blockIdx.x * 256 + threadIdx.x;
    if (node >= n) return;

    float4 f[NFEAT / 4];
    const float4* fp = (const float4*)(feat + (size_t)node * NFEAT);
#pragma unroll
    for (int i = 0; i < NFEAT / 4; ++i) f[i] = fp[i];

    float hv[DOUT];
    for (int j = 0; j < DOUT; ++j) {
        const float4* wp = (const float4*)(Ww + (size_t)j * NFEAT);  // wave-uniform -> s_load
        float acc = Wb[j];
#pragma unroll
        for (int i = 0; i < NFEAT / 4; ++i) {
            float4 w = wp[i];
            acc = fmaf(f[i].x, w.x, acc);
            acc = fmaf(f[i].y, w.y, acc);
            acc = fmaf(f[i].z, w.z, acc);
            acc = fmaf(f[i].w, w.w, acc);
        }
        hv[j] = acc;
    }

    float ss = 0.f, sd = 0.f;
#pragma unroll
    for (int j = 0; j < DOUT; ++j) {
        ss = fmaf(hv[j], attn_w[j], ss);
        sd = fmaf(hv[j], attn_w[DOUT + j], sd);
    }

    float4* hp = (float4*)(h + (size_t)node * DOUT);
#pragma unroll
    for (int i = 0; i < DOUT / 4; ++i)
        hp[i] = make_float4(hv[4 * i], hv[4 * i + 1], hv[4 * i + 2], hv[4 * i + 3]);
    s_src[node] = ss;
    s_dst[node] = sd;
}

// ---------------- CSR build: degree histogram ----------------
__global__ __launch_bounds__(256) void k_deg(
    const int* __restrict__ dst, int* __restrict__ deg, int nE)
{
    int e = blockIdx.x * 256 + threadIdx.x;
    if (e >= nE) return;
    atomicAdd(deg + dst[e], 1);
}

// ---------------- exclusive scan, 3 kernels ----------------
__global__ __launch_bounds__(256) void k_scan1(
    const int* __restrict__ deg, int* __restrict__ rowptr, int* __restrict__ partial, int n)
{
    __shared__ int s[256];
    int i = blockIdx.x * 256 + threadIdx.x;
    int v = (i < n) ? deg[i] : 0;
    s[threadIdx.x] = v;
    __syncthreads();
#pragma unroll
    for (int off = 1; off < 256; off <<= 1) {
        int t = (threadIdx.x >= off) ? s[threadIdx.x - off] : 0;
        __syncthreads();
        s[threadIdx.x] += t;
        __syncthreads();
    }
    if (i < n) rowptr[i] = s[threadIdx.x] - v;  // block-local exclusive
    if (threadIdx.x == 255) partial[blockIdx.x] = s[255];
}

__global__ __launch_bounds__(512) void k_scan2(int* __restrict__ partial, int nb)
{
    __shared__ int s[512];
    int t = threadIdx.x;
    int v = (t < nb) ? partial[t] : 0;
    s[t] = v;
    __syncthreads();
#pragma unroll
    for (int off = 1; off < 512; off <<= 1) {
        int x = (t >= off) ? s[t - off] : 0;
        __syncthreads();
        s[t] += x;
        __syncthreads();
    }
    if (t < nb) partial[t] = s[t] - v;       // exclusive
    if (t == 511) partial[nb] = s[511];      // total
}

__global__ __launch_bounds__(256) void k_scan3(
    int* __restrict__ rowptr, const int* __restrict__ partial, int n, int nb)
{
    int i = blockIdx.x * 256 + threadIdx.x;
    if (i < n) rowptr[i] += partial[i >> 8];
    else if (i == n) rowptr[n] = partial[nb];
}

// ---------------- bucket fill: group edges by dst ----------------
__global__ __launch_bounds__(256) void k_fill(
    const int* __restrict__ src, const int* __restrict__ dst,
    const int* __restrict__ rowptr, int* __restrict__ cursor,
    const float* __restrict__ s_src,
    int* __restrict__ esrc, float* __restrict__ escore, int nE)
{
    int e = blockIdx.x * 256 + threadIdx.x;
    if (e >= nE) return;
    int d = dst[e];
    int p = atomicAdd(cursor + d, 1);
    int slot = rowptr[d] + p;
    int s = src[e];
    esrc[slot] = s;
    escore[slot] = s_src[s];
}

// ---------------- fused softmax + aggregate: one wave per dst node ----------------
__global__ __launch_bounds__(256) void k_agg(
    const float* __restrict__ h, const float* __restrict__ s_dst,
    const float* __restrict__ attn_b,
    const int* __restrict__ rowptr, const int* __restrict__ esrc,
    const float* __restrict__ escore,
    float* __restrict__ out, int n)
{
    int wave = threadIdx.x >> 6;
    int lane = threadIdx.x & 63;
    int d = blockIdx.x * 4 + wave;
    if (d >= n) return;

    int start = rowptr[d], end = rowptr[d + 1];
    if (start == end) {
        if (lane < DOUT) out[(size_t)d * DOUT + lane] = 0.f;
        return;
    }
    float base = s_dst[d] + attn_b[0];

    // pass 1: lane-parallel max
    float mloc = -1e30f;
    for (int k = start + lane; k < end; k += 64) {
        float v = escore[k] + base;
        v = (v > 0.f) ? v : 0.2f * v;
        mloc = fmaxf(mloc, v);
    }
#pragma unroll
    for (int o = 32; o >= 1; o >>= 1) mloc = fmaxf(mloc, __shfl_xor(mloc, o, 64));
    float m = mloc;

    // pass 2: serial edges, lanes 0..47 accumulate feature j
    float acc = 0.f, den = 0.f;
    for (int k = start; k < end; ++k) {
        float v = escore[k] + base;
        v = (v > 0.f) ? v : 0.2f * v;
        float x = __expf(v - m);
        den += x;
        int s = esrc[k];
        if (lane < DOUT) acc = fmaf(x, h[(size_t)s * DOUT + lane], acc);
    }
    if (lane < DOUT) out[(size_t)d * DOUT + lane] = acc / den;
}

extern "C" void kernel_launch(void* const* d_in, const int* in_sizes, int n_in,
                              void* d_out, int out_size, void* d_ws, size_t ws_size,
                              hipStream_t stream) {
    const float* feat   = (const float*)d_in[0];
    const float* Ww     = (const float*)d_in[1];
    const float* Wb     = (const float*)d_in[2];
    const float* attn_w = (const float*)d_in[3];
    const float* attn_b = (const float*)d_in[4];
    const int*   src    = (const int*)d_in[5];
    const int*   dst    = (const int*)d_in[6];

    int n  = in_sizes[0] / NFEAT;   // 100000
    int nE = in_sizes[5];           // 1600000
    int nb = (n + 255) / 256;       // scan blocks
    float* out = (float*)d_out;

    // workspace layout
    float* ws      = (float*)d_ws;
    float* h       = ws;                           // n*48
    float* s_src   = h + (size_t)n * DOUT;         // n
    float* s_dst   = s_src + n;                    // n
    int*   deg     = (int*)(s_dst + n);            // n
    int*   rowptr  = deg + n;                      // n+1
    int*   partial = rowptr + (n + 1);             // nb+1
    int*   cursor  = partial + (nb + 1);           // n
    int*   esrc    = cursor + n;                   // nE
    float* escore  = (float*)(esrc + nE);          // nE

    hipMemsetAsync(deg,    0, (size_t)n * sizeof(int), stream);
    hipMemsetAsync(cursor, 0, (size_t)n * sizeof(int), stream);

    k_proj<<<(n + 255) / 256, 256, 0, stream>>>(feat, Ww, Wb, attn_w, h, s_src, s_dst, n);
    k_deg<<<(nE + 255) / 256, 256, 0, stream>>>(dst, deg, nE);
    k_scan1<<<nb, 256, 0, stream>>>(deg, rowptr, partial, n);
    k_scan2<<<1, 512, 0, stream>>>(partial, nb);
    k_scan3<<<(n + 1 + 255) / 256, 256, 0, stream>>>(rowptr, partial, n, nb);
    k_fill<<<(nE + 255) / 256, 256, 0, stream>>>(src, dst, rowptr, cursor, s_src, esrc, escore, nE);
    k_agg<<<(n + 3) / 4, 256, 0, stream>>>(h, s_dst, attn_b, rowptr, esrc, escore, out, n);
}

// Round 3
// 406.928 us; speedup vs baseline: 1.6225x; 1.5963x over previous
//
#include <hip/hip_runtime.h>

#define NFEAT 128
#define DOUT 48

// ---------------- kernel A: h = feat @ W^T + b ; s_src/s_dst dots ----------------
// K chunked 4x32 to keep VGPR ~100 (occupancy) and W slice (6KB) scalar-cache resident.
__global__ __launch_bounds__(256) void k_proj(
    const float* __restrict__ feat, const float* __restrict__ Ww,
    const float* __restrict__ Wb, const float* __restrict__ attn_w,
    float* __restrict__ h, float* __restrict__ s_src, float* __restrict__ s_dst,
    int n)
{
    int node = blockIdx.x * 256 + threadIdx.x;
    if (node >= n) return;

    float hv[DOUT];
#pragma unroll
    for (int j = 0; j < DOUT; ++j) hv[j] = Wb[j];

    const float4* fp = (const float4*)(feat + (size_t)node * NFEAT);
#pragma unroll 1
    for (int c = 0; c < 4; ++c) {
        float4 f[8];
#pragma unroll
        for (int i = 0; i < 8; ++i) f[i] = fp[c * 8 + i];
#pragma unroll 1
        for (int j = 0; j < DOUT; ++j) {
            const float4* wp = (const float4*)(Ww + (size_t)j * NFEAT + c * 32);  // wave-uniform
            float acc = hv[j];
#pragma unroll
            for (int i = 0; i < 8; ++i) {
                float4 w = wp[i];
                acc = fmaf(f[i].x, w.x, acc);
                acc = fmaf(f[i].y, w.y, acc);
                acc = fmaf(f[i].z, w.z, acc);
                acc = fmaf(f[i].w, w.w, acc);
            }
            hv[j] = acc;
        }
    }

    float ss = 0.f, sd = 0.f;
#pragma unroll
    for (int j = 0; j < DOUT; ++j) {
        ss = fmaf(hv[j], attn_w[j], ss);
        sd = fmaf(hv[j], attn_w[DOUT + j], sd);
    }

    float4* hp = (float4*)(h + (size_t)node * DOUT);
#pragma unroll
    for (int i = 0; i < DOUT / 4; ++i)
        hp[i] = make_float4(hv[4 * i], hv[4 * i + 1], hv[4 * i + 2], hv[4 * i + 3]);
    s_src[node] = ss;
    s_dst[node] = sd;
}

// ---------------- CSR build: degree histogram ----------------
__global__ __launch_bounds__(256) void k_deg(
    const int* __restrict__ dst, int* __restrict__ deg, int nE)
{
    int e = blockIdx.x * 256 + threadIdx.x;
    if (e >= nE) return;
    atomicAdd(deg + dst[e], 1);
}

// ---------------- exclusive scan, 3 kernels ----------------
__global__ __launch_bounds__(256) void k_scan1(
    const int* __restrict__ deg, int* __restrict__ rowptr, int* __restrict__ partial, int n)
{
    __shared__ int s[256];
    int i = blockIdx.x * 256 + threadIdx.x;
    int v = (i < n) ? deg[i] : 0;
    s[threadIdx.x] = v;
    __syncthreads();
#pragma unroll
    for (int off = 1; off < 256; off <<= 1) {
        int t = (threadIdx.x >= off) ? s[threadIdx.x - off] : 0;
        __syncthreads();
        s[threadIdx.x] += t;
        __syncthreads();
    }
    if (i < n) rowptr[i] = s[threadIdx.x] - v;  // block-local exclusive
    if (threadIdx.x == 255) partial[blockIdx.x] = s[255];
}

__global__ __launch_bounds__(512) void k_scan2(int* __restrict__ partial, int nb)
{
    __shared__ int s[512];
    int t = threadIdx.x;
    int v = (t < nb) ? partial[t] : 0;
    s[t] = v;
    __syncthreads();
#pragma unroll
    for (int off = 1; off < 512; off <<= 1) {
        int x = (t >= off) ? s[t - off] : 0;
        __syncthreads();
        s[t] += x;
        __syncthreads();
    }
    if (t < nb) partial[t] = s[t] - v;       // exclusive
    if (t == 511) partial[nb] = s[511];      // total
}

__global__ __launch_bounds__(256) void k_scan3(
    int* __restrict__ rowptr, const int* __restrict__ partial, int n, int nb)
{
    int i = blockIdx.x * 256 + threadIdx.x;
    if (i < n) rowptr[i] += partial[i >> 8];
    else if (i == n) rowptr[n] = partial[nb];
}

// ---------------- bucket fill: group edges by dst, score precomputed ----------------
__global__ __launch_bounds__(256) void k_fill(
    const int* __restrict__ src, const int* __restrict__ dst,
    const int* __restrict__ rowptr, int* __restrict__ cursor,
    const float* __restrict__ s_src, const float* __restrict__ s_dst,
    const float* __restrict__ attn_b,
    int2* __restrict__ epack, int nE)
{
    int e = blockIdx.x * 256 + threadIdx.x;
    if (e >= nE) return;
    int d = dst[e];
    int s = src[e];
    int p = atomicAdd(cursor + d, 1);
    int slot = rowptr[d] + p;
    float v = s_src[s] + s_dst[d] + attn_b[0];
    v = (v > 0.f) ? v : 0.2f * v;             // leaky_relu(0.2)
    epack[slot] = make_int2(s, __float_as_int(v));  // one 8B scatter
}

// ---------------- fused softmax + aggregate: one wave per dst node ----------------
// 4 groups of 16 lanes; each group handles a different edge (4 gathers in flight),
// each lane loads 3 contiguous floats of the 48-float h row (192B coalesced/edge).
__global__ __launch_bounds__(256) void k_agg(
    const float* __restrict__ h,
    const int* __restrict__ rowptr, const int2* __restrict__ epack,
    float* __restrict__ out, int n)
{
    int wave = threadIdx.x >> 6;
    int lane = threadIdx.x & 63;
    int d = blockIdx.x * 4 + wave;
    if (d >= n) return;

    int start = rowptr[d], end = rowptr[d + 1];
    int g = lane >> 4;       // group 0..3
    int sub = lane & 15;     // lane within group

    if (start == end) {
        if (lane < 16) {
            float* op = out + (size_t)d * DOUT + sub * 3;
            op[0] = 0.f; op[1] = 0.f; op[2] = 0.f;
        }
        return;
    }

    // pass 1: lane-parallel max over scores (also warms L1 for pass 2)
    float mloc = -1e30f;
    for (int k = start + lane; k < end; k += 64)
        mloc = fmaxf(mloc, __int_as_float(epack[k].y));
#pragma unroll
    for (int o = 32; o >= 1; o >>= 1) mloc = fmaxf(mloc, __shfl_xor(mloc, o, 64));
    float m = mloc;

    // pass 2: group-parallel edges
    float a0 = 0.f, a1 = 0.f, a2 = 0.f, den = 0.f;
    for (int k = start + g; k < end; k += 4) {
        int2 pk = epack[k];                       // 16 lanes same addr (L1 broadcast)
        float x = __expf(__int_as_float(pk.y) - m);
        den += x;
        const float* hr = h + (size_t)pk.x * DOUT + sub * 3;
        a0 = fmaf(x, hr[0], a0);
        a1 = fmaf(x, hr[1], a1);
        a2 = fmaf(x, hr[2], a2);
    }
    // reduce across the 4 groups (xor 16, 32)
#pragma unroll
    for (int o = 16; o <= 32; o <<= 1) {
        a0  += __shfl_xor(a0, o, 64);
        a1  += __shfl_xor(a1, o, 64);
        a2  += __shfl_xor(a2, o, 64);
        den += __shfl_xor(den, o, 64);
    }
    if (lane < 16) {
        float inv = 1.f / den;
        float* op = out + (size_t)d * DOUT + sub * 3;
        op[0] = a0 * inv;
        op[1] = a1 * inv;
        op[2] = a2 * inv;
    }
}

extern "C" void kernel_launch(void* const* d_in, const int* in_sizes, int n_in,
                              void* d_out, int out_size, void* d_ws, size_t ws_size,
                              hipStream_t stream) {
    const float* feat   = (const float*)d_in[0];
    const float* Ww     = (const float*)d_in[1];
    const float* Wb     = (const float*)d_in[2];
    const float* attn_w = (const float*)d_in[3];
    const float* attn_b = (const float*)d_in[4];
    const int*   src    = (const int*)d_in[5];
    const int*   dst    = (const int*)d_in[6];

    int n  = in_sizes[0] / NFEAT;   // 100000
    int nE = in_sizes[5];           // 1600000
    int nb = (n + 255) / 256;       // scan blocks (<=512)
    float* out = (float*)d_out;

    // workspace layout
    float* ws      = (float*)d_ws;
    float* h       = ws;                           // n*48
    float* s_src   = h + (size_t)n * DOUT;         // n
    float* s_dst   = s_src + n;                    // n
    int*   deg     = (int*)(s_dst + n);            // n
    int*   rowptr  = deg + n;                      // n+1
    int*   partial = rowptr + (n + 1);             // nb+1
    int*   cursor  = partial + (nb + 1);           // n
    int2*  epack   = (int2*)(cursor + n);          // nE (src, lrelu score)

    hipMemsetAsync(deg,    0, (size_t)n * sizeof(int), stream);
    hipMemsetAsync(cursor, 0, (size_t)n * sizeof(int), stream);

    k_proj<<<(n + 255) / 256, 256, 0, stream>>>(feat, Ww, Wb, attn_w, h, s_src, s_dst, n);
    k_deg<<<(nE + 255) / 256, 256, 0, stream>>>(dst, deg, nE);
    k_scan1<<<nb, 256, 0, stream>>>(deg, rowptr, partial, n);
    k_scan2<<<1, 512, 0, stream>>>(partial, nb);
    k_scan3<<<(n + 1 + 255) / 256, 256, 0, stream>>>(rowptr, partial, n, nb);
    k_fill<<<(nE + 255) / 256, 256, 0, stream>>>(src, dst, rowptr, cursor, s_src, s_dst, attn_b, epack, nE);
    k_agg<<<(n + 3) / 4, 256, 0, stream>>>(h, rowptr, epack, out, n);
}